// Round 2
// baseline (2631.313 us; speedup 1.0000x reference)
//
#include <hip/hip_runtime.h>
#include <hip/hip_bf16.h>

// MANO forward: B=16384, V=778, J=16, NB=10, NPCA=6.
// R4: BB=8 batch-tiled + transposed posedirs in workspace (float4 loads:
// 405 scalar -> 102 dwordx4 per vertex-thread), dwordx3 packed output
// stores (kill the 5.8x write amplification seen in R3), register diet
// (__launch_bounds__(256,3)). Runtime dtype detect retained; fallback to
// non-transposed path if workspace too small.

typedef __hip_bfloat16 bf16;
typedef unsigned short u16;

#define BATCH 16384
#define NVERT 778
#define NJOINT 16
#define NSHAPE 10
#define NPCA 6
#define NPF 135                // (J-1)*9
#define PD_COLS (NVERT * 3)    // 2334
#define VERT_ELEMS ((size_t)BATCH * NVERT * 3)
#define BB 8                   // batches per block
#define NBLK (BATCH / BB)      // 2048
#define NCHUNK 34              // ceil(135/4)
#define PDT_ELEMS (NCHUNK * PD_COLS * 4)   // 317,424 floats
#define PDT_BYTE_OFF 4096

__device__ __forceinline__ float b2f(bf16 x) { return __bfloat162float(x); }
__device__ __forceinline__ bf16  f2b(float x) { return __float2bfloat16(x); }

// PARENTS = [-1,0,1,2,0,4,5,0,7,8,0,10,11,0,13,14]
__device__ __forceinline__ int parent_of(int j) {
    return (j == 0) ? -1 : (((j - 1) % 3 == 0) ? 0 : j - 1);
}

template <typename T> __device__ __forceinline__ float ldv(const void* p, size_t i);
template <> __device__ __forceinline__ float ldv<float>(const void* p, size_t i) {
    return ((const float*)p)[i];
}
template <> __device__ __forceinline__ float ldv<bf16>(const void* p, size_t i) {
    return b2f(((const bf16*)p)[i]);
}

template <typename T> __device__ __forceinline__ void stv(void* p, size_t i, float v);
template <> __device__ __forceinline__ void stv<float>(void* p, size_t i, float v) {
    ((float*)p)[i] = v;
}
template <> __device__ __forceinline__ void stv<bf16>(void* p, size_t i, float v) {
    ((bf16*)p)[i] = f2b(v);
}

struct F3 { float x, y, z; };

// packed 12B store (fp32) / 3 scalar (bf16)
template <typename T> __device__ __forceinline__ void st3(void* p, size_t i,
                                                          float a, float b, float c);
template <> __device__ __forceinline__ void st3<float>(void* p, size_t i,
                                                       float a, float b, float c) {
    *(F3*)((float*)p + i) = F3{a, b, c};
}
template <> __device__ __forceinline__ void st3<bf16>(void* p, size_t i,
                                                      float a, float b, float c) {
    bf16* o = (bf16*)p + i;
    o[0] = f2b(a); o[1] = f2b(b); o[2] = f2b(c);
}

// ---------------------------------------------------------------------------
// Kernel 0: dtype detector. flag=1 -> fp32.
// ---------------------------------------------------------------------------
__global__ void detect_dtype(const u16* __restrict__ betas_u, int* __restrict__ flag) {
    __shared__ int s_cnt[256];
    int tid = threadIdx.x;
    int cnt = 0;
    for (int i = tid; i < BATCH * NSHAPE; i += 256) {
        int e = (betas_u[i] >> 7) & 0xFF;
        cnt += (e >= 134) ? 1 : 0;
    }
    s_cnt[tid] = cnt;
    __syncthreads();
    for (int s = 128; s > 0; s >>= 1) {
        if (tid < s) s_cnt[tid] += s_cnt[tid + s];
        __syncthreads();
    }
    if (tid == 0) *flag = (s_cnt[0] > 1000) ? 1 : 0;
}

// ---------------------------------------------------------------------------
// Kernel A: fold J_regressor into v_template and shapedirs.
// ---------------------------------------------------------------------------
template <typename T>
__device__ void precompute_body(const void* Jreg, const void* v_template,
                                const void* shapedirs, float* jt, float* jsd) {
    int idx = blockIdx.x * blockDim.x + threadIdx.x;
    if (idx >= 48 + 480) return;
    if (idx < 48) {
        int j = idx / 3, k = idx % 3;
        float acc = 0.f;
        for (int v = 0; v < NVERT; ++v)
            acc += ldv<T>(Jreg, j * NVERT + v) * ldv<T>(v_template, v * 3 + k);
        jt[idx] = acc;
    } else {
        int o = idx - 48;
        int jk = o / NSHAPE, l = o % NSHAPE;
        int j = jk / 3, k = jk % 3;
        float acc = 0.f;
        for (int v = 0; v < NVERT; ++v)
            acc += ldv<T>(Jreg, j * NVERT + v) * ldv<T>(shapedirs, (v * 3 + k) * NSHAPE + l);
        jsd[o] = acc;
    }
}

__global__ void precompute_kernel(const void* Jreg, const void* v_template,
                                  const void* shapedirs, const int* __restrict__ flag,
                                  float* jt, float* jsd) {
    if (*flag) precompute_body<float>(Jreg, v_template, shapedirs, jt, jsd);
    else       precompute_body<bf16 >(Jreg, v_template, shapedirs, jt, jsd);
}

// ---------------------------------------------------------------------------
// Kernel A2: transpose posedirs -> pdT[c][r][j] = posedirs[4c+j][r] (fp32),
// zero-padded for p >= 135. Writes coalesced; reads strided (one-shot, tiny).
// ---------------------------------------------------------------------------
template <typename T>
__device__ void transpose_body(const void* pd, float* __restrict__ pdT) {
    int idx = blockIdx.x * blockDim.x + threadIdx.x;
    if (idx >= PDT_ELEMS) return;
    int j = idx & 3;
    int rc = idx >> 2;
    int r = rc % PD_COLS;
    int c = rc / PD_COLS;
    int p = c * 4 + j;
    pdT[idx] = (p < NPF) ? ldv<T>(pd, (size_t)p * PD_COLS + r) : 0.f;
}

__global__ void transpose_kernel(const void* pd, const int* __restrict__ flag,
                                 float* __restrict__ pdT) {
    if (*flag) transpose_body<float>(pd, pdT);
    else       transpose_body<bf16 >(pd, pdT);
}

// ---------------------------------------------------------------------------
// Kernel B: fused batch-tiled kernel. blockIdx.x = batch-tile of BB. 256 thr.
// ---------------------------------------------------------------------------
struct __align__(16) SmemB {
    float pf[BB][136];            // 135 + zero pad for float4 chunks
    float rel[BB][NJOINT][12];    // rel transforms, float4-aligned rows
    float tm[BB][NJOINT][12];     // local transforms (stage 1 scratch)
    float joints[BB][NJOINT][3];
    float beta[BB][NSHAPE];
    float transl[BB][3];
};                                // ~18.6 KB

template <typename T, bool TRP>
__device__ void mano_body(const void* betas, const void* orient,
                          const void* hand_pose, const void* transl,
                          const void* hc, const void* pose_mean,
                          const void* v_template, const void* shapedirs,
                          const void* posedirs, const void* lbsw,
                          const float* __restrict__ jt, const float* __restrict__ jsd,
                          const float* __restrict__ pdT,
                          void* out_base, SmemB& s) {
    const int tid = threadIdx.x;
    const int b0 = blockIdx.x * BB;

    // stage in beta / transl (consumed after the syncthreads below)
    if (tid >= 128 && tid < 128 + BB * NSHAPE) {
        int o = tid - 128;
        int q = o / NSHAPE, l = o % NSHAPE;
        s.beta[q][l] = ldv<T>(betas, (size_t)(b0 + q) * NSHAPE + l);
    }
    if (tid >= 224 && tid < 224 + BB * 3) {
        int o = tid - 224;
        int q = o / 3, k = o % 3;
        s.transl[q][k] = ldv<T>(transl, (size_t)(b0 + q) * 3 + k);
    }

    // ---- stage 1a (threads 0..127): (bb, j) -> R, regressed joints ----
    const int bb = tid >> 4;
    const int j  = tid & 15;
    float R[9];
    float jx[3];
    if (tid < BB * NJOINT) {
        const int b = b0 + bb;
        float p0, p1, p2;
        if (j == 0) {
            p0 = ldv<T>(orient, (size_t)b * 3 + 0) + ldv<T>(pose_mean, 0);
            p1 = ldv<T>(orient, (size_t)b * 3 + 1) + ldv<T>(pose_mean, 1);
            p2 = ldv<T>(orient, (size_t)b * 3 + 2) + ldv<T>(pose_mean, 2);
        } else {
            int base = 3 * (j - 1);
            p0 = ldv<T>(pose_mean, 3 * j + 0);
            p1 = ldv<T>(pose_mean, 3 * j + 1);
            p2 = ldv<T>(pose_mean, 3 * j + 2);
            #pragma unroll
            for (int c = 0; c < NPCA; ++c) {
                float hp = ldv<T>(hand_pose, (size_t)b * NPCA + c);
                p0 += hp * ldv<T>(hc, c * 45 + base + 0);
                p1 += hp * ldv<T>(hc, c * 45 + base + 1);
                p2 += hp * ldv<T>(hc, c * 45 + base + 2);
            }
        }

        float r0 = p0 + 1e-8f, r1 = p1 + 1e-8f, r2 = p2 + 1e-8f;
        float angle = sqrtf(r0 * r0 + r1 * r1 + r2 * r2);
        float inv = 1.f / angle;
        float ax = p0 * inv, ay = p1 * inv, az = p2 * inv;
        float sn = sinf(angle);
        float cc1 = 1.f - cosf(angle);
        R[0] = 1.f + cc1 * (-az * az - ay * ay);
        R[1] = -sn * az + cc1 * ax * ay;
        R[2] =  sn * ay + cc1 * ax * az;
        R[3] =  sn * az + cc1 * ax * ay;
        R[4] = 1.f + cc1 * (-az * az - ax * ax);
        R[5] = -sn * ax + cc1 * ay * az;
        R[6] = -sn * ay + cc1 * ax * az;
        R[7] =  sn * ax + cc1 * ay * az;
        R[8] = 1.f + cc1 * (-ax * ax - ay * ay);

        #pragma unroll
        for (int k = 0; k < 3; ++k) {
            float acc = jt[j * 3 + k];
            #pragma unroll
            for (int l = 0; l < NSHAPE; ++l)
                acc += jsd[(j * 3 + k) * NSHAPE + l] * ldv<T>(betas, (size_t)(b0 + bb) * NSHAPE + l);
            jx[k] = acc;
            s.joints[bb][j][k] = acc;
        }
    }
    __syncthreads();

    // ---- stage 1b: local transform [R | joint - parent_joint] ----
    if (tid < BB * NJOINT) {
        int par = parent_of(j);
        #pragma unroll
        for (int m = 0; m < 3; ++m) {
            float t = jx[m] - (j > 0 ? s.joints[bb][par][m] : 0.f);
            s.tm[bb][j][m * 4 + 0] = R[m * 3 + 0];
            s.tm[bb][j][m * 4 + 1] = R[m * 3 + 1];
            s.tm[bb][j][m * 4 + 2] = R[m * 3 + 2];
            s.tm[bb][j][m * 4 + 3] = t;
        }
    }
    __syncthreads();

    // ---- stage 1c: chain walk, rel transforms, pose feature, joints out ----
    if (tid < BB * NJOINT) {
        int stack[3];
        int depth = 0;
        int i = j;
        while (i != 0 && depth < 3) { stack[depth++] = i; i = parent_of(i); }

        float G[12];
        #pragma unroll
        for (int t = 0; t < 12; ++t) G[t] = s.tm[bb][0][t];
        for (int d = depth - 1; d >= 0; --d) {
            const float* Tc = s.tm[bb][stack[d]];
            float Gn[12];
            #pragma unroll
            for (int m = 0; m < 3; ++m) {
                #pragma unroll
                for (int n = 0; n < 4; ++n) {
                    float acc = G[m * 4 + 0] * Tc[0 * 4 + n] +
                                G[m * 4 + 1] * Tc[1 * 4 + n] +
                                G[m * 4 + 2] * Tc[2 * 4 + n];
                    if (n == 3) acc += G[m * 4 + 3];
                    Gn[m * 4 + n] = acc;
                }
            }
            #pragma unroll
            for (int t = 0; t < 12; ++t) G[t] = Gn[t];
        }

        // posed joints out (+ transl) — joints section follows vertices
        size_t jo = VERT_ELEMS + ((size_t)(b0 + bb) * NJOINT + j) * 3;
        st3<T>(out_base, jo,
               G[0 * 4 + 3] + s.transl[bb][0],
               G[1 * 4 + 3] + s.transl[bb][1],
               G[2 * 4 + 3] + s.transl[bb][2]);

        // rel transform: [R_full | t - R_full @ joint]
        #pragma unroll
        for (int m = 0; m < 3; ++m) {
            float rb = G[m * 4 + 3] -
                       (G[m * 4 + 0] * jx[0] + G[m * 4 + 1] * jx[1] + G[m * 4 + 2] * jx[2]);
            s.rel[bb][j][m * 4 + 0] = G[m * 4 + 0];
            s.rel[bb][j][m * 4 + 1] = G[m * 4 + 1];
            s.rel[bb][j][m * 4 + 2] = G[m * 4 + 2];
            s.rel[bb][j][m * 4 + 3] = rb;
        }

        if (j > 0) {
            float* po = s.pf[bb] + (j - 1) * 9;
            po[0] = R[0] - 1.f; po[1] = R[1];       po[2] = R[2];
            po[3] = R[3];       po[4] = R[4] - 1.f; po[5] = R[5];
            po[6] = R[6];       po[7] = R[7];       po[8] = R[8] - 1.f;
        } else {
            s.pf[bb][135] = 0.f;   // pad so float4 chunk 33 is harmless
        }
    }
    __syncthreads();

    // ---- stage 2: per-vertex, all BB batches in registers ----
    for (int v = tid; v < NVERT; v += 256) {
        const int v3 = v * 3;

        float a[BB][3];
        {
            const float t0 = ldv<T>(v_template, v3 + 0);
            const float t1 = ldv<T>(v_template, v3 + 1);
            const float t2 = ldv<T>(v_template, v3 + 2);
            #pragma unroll
            for (int q = 0; q < BB; ++q) { a[q][0] = t0; a[q][1] = t1; a[q][2] = t2; }
        }

        // shape blendshapes: 30 loads serve 8 batches
        #pragma unroll
        for (int l = 0; l < NSHAPE; ++l) {
            const float sd0 = ldv<T>(shapedirs, (size_t)v * 30 + 0 * NSHAPE + l);
            const float sd1 = ldv<T>(shapedirs, (size_t)v * 30 + 1 * NSHAPE + l);
            const float sd2 = ldv<T>(shapedirs, (size_t)v * 30 + 2 * NSHAPE + l);
            #pragma unroll
            for (int q = 0; q < BB; ++q) {
                const float be = s.beta[q][l];
                a[q][0] += be * sd0;
                a[q][1] += be * sd1;
                a[q][2] += be * sd2;
            }
        }

        // pose blendshapes
        if constexpr (TRP) {
            // pdT[c][r][0..3]: float4 per (chunk, row). 102 dwordx4 total.
            const float4* __restrict__ pdT4 = (const float4*)pdT;
            #pragma unroll 2
            for (int c = 0; c < NCHUNK; ++c) {
                const float4 px = pdT4[(size_t)c * PD_COLS + v3 + 0];
                const float4 py = pdT4[(size_t)c * PD_COLS + v3 + 1];
                const float4 pz = pdT4[(size_t)c * PD_COLS + v3 + 2];
                #pragma unroll
                for (int q = 0; q < BB; ++q) {
                    const float4 f = *(const float4*)&s.pf[q][c * 4];
                    a[q][0] += f.x * px.x + f.y * px.y + f.z * px.z + f.w * px.w;
                    a[q][1] += f.x * py.x + f.y * py.y + f.z * py.z + f.w * py.w;
                    a[q][2] += f.x * pz.x + f.y * pz.y + f.z * pz.z + f.w * pz.w;
                }
            }
        } else {
            #pragma unroll 1
            for (int c = 0; c < NCHUNK; ++c) {
                const int p = c * 4;
                float pdx[4], pdy[4], pdz[4];
                #pragma unroll
                for (int qq = 0; qq < 3; ++qq) {
                    pdx[qq] = ldv<T>(posedirs, (size_t)(p + qq) * PD_COLS + v3 + 0);
                    pdy[qq] = ldv<T>(posedirs, (size_t)(p + qq) * PD_COLS + v3 + 1);
                    pdz[qq] = ldv<T>(posedirs, (size_t)(p + qq) * PD_COLS + v3 + 2);
                }
                if (p + 3 < NPF) {
                    pdx[3] = ldv<T>(posedirs, (size_t)(p + 3) * PD_COLS + v3 + 0);
                    pdy[3] = ldv<T>(posedirs, (size_t)(p + 3) * PD_COLS + v3 + 1);
                    pdz[3] = ldv<T>(posedirs, (size_t)(p + 3) * PD_COLS + v3 + 2);
                } else {
                    pdx[3] = 0.f; pdy[3] = 0.f; pdz[3] = 0.f;
                }
                #pragma unroll
                for (int q = 0; q < BB; ++q) {
                    const float4 f = *(const float4*)&s.pf[q][p];
                    a[q][0] += f.x * pdx[0] + f.y * pdx[1] + f.z * pdx[2] + f.w * pdx[3];
                    a[q][1] += f.x * pdy[0] + f.y * pdy[1] + f.z * pdy[2] + f.w * pdy[3];
                    a[q][2] += f.x * pdz[0] + f.y * pdz[1] + f.z * pdz[2] + f.w * pdz[3];
                }
            }
        }

        // LBS weights (after pose loop to limit live registers)
        float w[NJOINT];
        if constexpr (sizeof(T) == 4) {
            const float4* wl = (const float4*)((const float*)lbsw + (size_t)v * NJOINT);
            #pragma unroll
            for (int g = 0; g < 4; ++g) {
                const float4 t = wl[g];
                w[g * 4 + 0] = t.x; w[g * 4 + 1] = t.y;
                w[g * 4 + 2] = t.z; w[g * 4 + 3] = t.w;
            }
        } else {
            #pragma unroll
            for (int jj = 0; jj < NJOINT; ++jj)
                w[jj] = ldv<T>(lbsw, (size_t)v * NJOINT + jj);
        }

        // LBS + output. rel rows read as uniform float4 broadcasts.
        #pragma unroll
        for (int q = 0; q < BB; ++q) {
            float Tm[12];
            #pragma unroll
            for (int t = 0; t < 12; ++t) Tm[t] = 0.f;
            #pragma unroll
            for (int jj = 0; jj < NJOINT; ++jj) {
                const float4 r0 = *(const float4*)&s.rel[q][jj][0];
                const float4 r1 = *(const float4*)&s.rel[q][jj][4];
                const float4 r2 = *(const float4*)&s.rel[q][jj][8];
                const float wj = w[jj];
                Tm[0] += wj * r0.x; Tm[1]  += wj * r0.y; Tm[2]  += wj * r0.z; Tm[3]  += wj * r0.w;
                Tm[4] += wj * r1.x; Tm[5]  += wj * r1.y; Tm[6]  += wj * r1.z; Tm[7]  += wj * r1.w;
                Tm[8] += wj * r2.x; Tm[9]  += wj * r2.y; Tm[10] += wj * r2.z; Tm[11] += wj * r2.w;
            }
            const size_t vo = ((size_t)(b0 + q) * NVERT + v) * 3;
            const float o0 = Tm[0] * a[q][0] + Tm[1] * a[q][1] + Tm[2]  * a[q][2] + Tm[3]  + s.transl[q][0];
            const float o1 = Tm[4] * a[q][0] + Tm[5] * a[q][1] + Tm[6]  * a[q][2] + Tm[7]  + s.transl[q][1];
            const float o2 = Tm[8] * a[q][0] + Tm[9] * a[q][1] + Tm[10] * a[q][2] + Tm[11] + s.transl[q][2];
            st3<T>(out_base, vo, o0, o1, o2);
        }
    }
}

template <bool TRP>
__global__ __launch_bounds__(256, 3) void mano_fused(
    const void* betas, const void* orient, const void* hand_pose,
    const void* transl, const void* hc, const void* pose_mean,
    const void* v_template, const void* shapedirs, const void* posedirs,
    const void* lbsw, const int* __restrict__ flag,
    const float* __restrict__ jt, const float* __restrict__ jsd,
    const float* __restrict__ pdT,
    void* out_base) {
    __shared__ SmemB s;
    if (*flag)
        mano_body<float, TRP>(betas, orient, hand_pose, transl, hc, pose_mean,
                              v_template, shapedirs, posedirs, lbsw, jt, jsd, pdT,
                              out_base, s);
    else
        mano_body<bf16, TRP>(betas, orient, hand_pose, transl, hc, pose_mean,
                             v_template, shapedirs, posedirs, lbsw, jt, jsd, pdT,
                             out_base, s);
}

// ---------------------------------------------------------------------------
extern "C" void kernel_launch(void* const* d_in, const int* in_sizes, int n_in,
                              void* d_out, int out_size, void* d_ws, size_t ws_size,
                              hipStream_t stream) {
    const void* betas      = d_in[0];
    const void* orient     = d_in[1];
    const void* hand_pose  = d_in[2];
    const void* transl     = d_in[3];
    const void* hc         = d_in[4];
    const void* pose_mean  = d_in[5];
    const void* v_template = d_in[6];
    const void* shapedirs  = d_in[7];
    const void* posedirs   = d_in[8];
    const void* Jreg       = d_in[9];
    const void* lbsw       = d_in[10];
    // d_in[11] (parents) intentionally ignored — tree is hardcoded.

    int*   flag = (int*)d_ws;
    float* jt   = (float*)d_ws + 16;
    float* jsd  = (float*)d_ws + 64;
    float* pdT  = (float*)((char*)d_ws + PDT_BYTE_OFF);

    const bool trp = ws_size >= (size_t)PDT_BYTE_OFF + (size_t)PDT_ELEMS * 4;

    hipLaunchKernelGGL(detect_dtype, dim3(1), dim3(256), 0, stream,
                       (const u16*)betas, flag);
    hipLaunchKernelGGL(precompute_kernel, dim3(3), dim3(192), 0, stream,
                       Jreg, v_template, shapedirs, flag, jt, jsd);
    if (trp) {
        hipLaunchKernelGGL(transpose_kernel, dim3((PDT_ELEMS + 255) / 256), dim3(256),
                           0, stream, posedirs, flag, pdT);
        hipLaunchKernelGGL(mano_fused<true>, dim3(NBLK), dim3(256), 0, stream,
                           betas, orient, hand_pose, transl, hc, pose_mean,
                           v_template, shapedirs, posedirs, lbsw, flag, jt, jsd,
                           pdT, d_out);
    } else {
        hipLaunchKernelGGL(mano_fused<false>, dim3(NBLK), dim3(256), 0, stream,
                           betas, orient, hand_pose, transl, hc, pose_mean,
                           v_template, shapedirs, posedirs, lbsw, flag, jt, jsd,
                           pdT, d_out);
    }
    (void)in_sizes; (void)n_in; (void)out_size; (void)ws_size;
}

// Round 4
// 2086.644 us; speedup vs baseline: 1.2610x; 1.2610x over previous
//
#include <hip/hip_runtime.h>
#include <hip/hip_bf16.h>

// MANO forward: B=16384, V=778, J=16, NB=10, NPCA=6.
// R5b: resubmit of R5 (bench infra failed twice; kernel never measured).
// Theory: the 156MB output stream churns L2 and evicts the batch-invariant
// pdT table (R4: FETCH 2.36GB ~= zero L2 reuse, WRITE amplified 10.6x).
// Fixes: (1) non-temporal output stores (evict-first), (2) BB=16 (halves
// pdT logical volume, 192 FMA per 3 loads), (3) 1-chunk-ahead register
// double-buffer on pdT with zero-padded chunk 34. LDS 25.3KB (tm/rel
// aliased) -> 6 blocks/CU; __launch_bounds__(256,4) targets <=128 VGPR.
// Change vs R5: union type-pun instead of __builtin_bit_cast (hardening).

typedef __hip_bfloat16 bf16;
typedef unsigned short u16;

#define BATCH 16384
#define NVERT 778
#define NJOINT 16
#define NSHAPE 10
#define NPCA 6
#define NPF 135                // (J-1)*9
#define PD_COLS (NVERT * 3)    // 2334
#define VERT_ELEMS ((size_t)BATCH * NVERT * 3)
#define BB 16                  // batches per block
#define NBLK (BATCH / BB)      // 1024
#define NCHUNK 34              // ceil(135/4)
#define PDT_CHUNKS 35          // +1 zero-padded chunk for branchless prefetch
#define PDT_ELEMS (PDT_CHUNKS * PD_COLS * 4)   // 326,760 floats
#define PDT_BYTE_OFF 4096

__device__ __forceinline__ float b2f(bf16 x) { return __bfloat162float(x); }
__device__ __forceinline__ bf16  f2b(float x) { return __float2bfloat16(x); }

// PARENTS = [-1,0,1,2,0,4,5,0,7,8,0,10,11,0,13,14]
__device__ __forceinline__ int parent_of(int j) {
    return (j == 0) ? -1 : (((j - 1) % 3 == 0) ? 0 : j - 1);
}

template <typename T> __device__ __forceinline__ float ldv(const void* p, size_t i);
template <> __device__ __forceinline__ float ldv<float>(const void* p, size_t i) {
    return ((const float*)p)[i];
}
template <> __device__ __forceinline__ float ldv<bf16>(const void* p, size_t i) {
    return b2f(((const bf16*)p)[i]);
}

__device__ __forceinline__ u16 bf_bits(float x) {
    union { bf16 h; u16 u; } cvt;
    cvt.h = f2b(x);
    return cvt.u;
}

// non-temporal 3-element store (evict-first: keep output stream out of L2 LRU)
template <typename T> __device__ __forceinline__ void st3(void* p, size_t i,
                                                          float a, float b, float c);
template <> __device__ __forceinline__ void st3<float>(void* p, size_t i,
                                                       float a, float b, float c) {
    float* o = (float*)p + i;
    __builtin_nontemporal_store(a, o + 0);
    __builtin_nontemporal_store(b, o + 1);
    __builtin_nontemporal_store(c, o + 2);
}
template <> __device__ __forceinline__ void st3<bf16>(void* p, size_t i,
                                                      float a, float b, float c) {
    u16* o = (u16*)p + i;
    __builtin_nontemporal_store(bf_bits(a), o + 0);
    __builtin_nontemporal_store(bf_bits(b), o + 1);
    __builtin_nontemporal_store(bf_bits(c), o + 2);
}

// ---------------------------------------------------------------------------
// Kernel 0: dtype detector. flag=1 -> fp32.
// ---------------------------------------------------------------------------
__global__ void detect_dtype(const u16* __restrict__ betas_u, int* __restrict__ flag) {
    __shared__ int s_cnt[256];
    int tid = threadIdx.x;
    int cnt = 0;
    for (int i = tid; i < BATCH * NSHAPE; i += 256) {
        int e = (betas_u[i] >> 7) & 0xFF;
        cnt += (e >= 134) ? 1 : 0;
    }
    s_cnt[tid] = cnt;
    __syncthreads();
    for (int s = 128; s > 0; s >>= 1) {
        if (tid < s) s_cnt[tid] += s_cnt[tid + s];
        __syncthreads();
    }
    if (tid == 0) *flag = (s_cnt[0] > 1000) ? 1 : 0;
}

// ---------------------------------------------------------------------------
// Kernel A: fold J_regressor into v_template and shapedirs.
// ---------------------------------------------------------------------------
template <typename T>
__device__ void precompute_body(const void* Jreg, const void* v_template,
                                const void* shapedirs, float* jt, float* jsd) {
    int idx = blockIdx.x * blockDim.x + threadIdx.x;
    if (idx >= 48 + 480) return;
    if (idx < 48) {
        int j = idx / 3, k = idx % 3;
        float acc = 0.f;
        for (int v = 0; v < NVERT; ++v)
            acc += ldv<T>(Jreg, j * NVERT + v) * ldv<T>(v_template, v * 3 + k);
        jt[idx] = acc;
    } else {
        int o = idx - 48;
        int jk = o / NSHAPE, l = o % NSHAPE;
        int j = jk / 3, k = jk % 3;
        float acc = 0.f;
        for (int v = 0; v < NVERT; ++v)
            acc += ldv<T>(Jreg, j * NVERT + v) * ldv<T>(shapedirs, (v * 3 + k) * NSHAPE + l);
        jsd[o] = acc;
    }
}

__global__ void precompute_kernel(const void* Jreg, const void* v_template,
                                  const void* shapedirs, const int* __restrict__ flag,
                                  float* jt, float* jsd) {
    if (*flag) precompute_body<float>(Jreg, v_template, shapedirs, jt, jsd);
    else       precompute_body<bf16 >(Jreg, v_template, shapedirs, jt, jsd);
}

// ---------------------------------------------------------------------------
// Kernel A2: transpose posedirs -> pdT[c][r][j] = posedirs[4c+j][r] (fp32),
// zero-padded for p >= 135 (incl. whole chunk 34 for branchless prefetch).
// ---------------------------------------------------------------------------
template <typename T>
__device__ void transpose_body(const void* pd, float* __restrict__ pdT) {
    int idx = blockIdx.x * blockDim.x + threadIdx.x;
    if (idx >= PDT_ELEMS) return;
    int j = idx & 3;
    int rc = idx >> 2;
    int r = rc % PD_COLS;
    int c = rc / PD_COLS;
    int p = c * 4 + j;
    pdT[idx] = (p < NPF) ? ldv<T>(pd, (size_t)p * PD_COLS + r) : 0.f;
}

__global__ void transpose_kernel(const void* pd, const int* __restrict__ flag,
                                 float* __restrict__ pdT) {
    if (*flag) transpose_body<float>(pd, pdT);
    else       transpose_body<bf16 >(pd, pdT);
}

// ---------------------------------------------------------------------------
// Kernel B: fused batch-tiled kernel. blockIdx.x = batch-tile of BB. 256 thr.
// ---------------------------------------------------------------------------
struct __align__(16) SmemB {
    float pf[BB][136];            // 135 + zero pad for float4 chunks   8704 B
    float tmrel[BB][NJOINT][12];  // stage1: local tm; then rel        12288 B
    float joints[BB][NJOINT][3];  //                                    3072 B
    float beta[BB][NSHAPE];       //                                     640 B
    float transl[BB][3];          //                                     192 B
    float hp[BB][NPCA];           //                                     384 B
};                                // 25,280 B -> 6 blocks/CU by LDS

template <typename T, bool TRP>
__device__ void mano_body(const void* betas, const void* orient,
                          const void* hand_pose, const void* transl,
                          const void* hc, const void* pose_mean,
                          const void* v_template, const void* shapedirs,
                          const void* posedirs, const void* lbsw,
                          const float* __restrict__ jt, const float* __restrict__ jsd,
                          const float* __restrict__ pdT,
                          void* out_base, SmemB& s) {
    const int tid = threadIdx.x;
    const int b0 = blockIdx.x * BB;

    // ---- stage 0: stage per-batch small inputs into LDS ----
    if (tid < BB * NSHAPE) {                       // 160 threads
        int q = tid / NSHAPE, l = tid % NSHAPE;
        s.beta[q][l] = ldv<T>(betas, (size_t)(b0 + q) * NSHAPE + l);
    } else if (tid < BB * NSHAPE + BB * 3) {       // 48 threads
        int o = tid - BB * NSHAPE;
        int q = o / 3, k = o % 3;
        s.transl[q][k] = ldv<T>(transl, (size_t)(b0 + q) * 3 + k);
    } else {                                       // 48 threads, 2 loads each
        int o = tid - (BB * NSHAPE + BB * 3);
        #pragma unroll
        for (int rep = 0; rep < 2; ++rep) {
            int oo = o + rep * 48;
            int q = oo / NPCA, c = oo % NPCA;
            s.hp[q][c] = ldv<T>(hand_pose, (size_t)(b0 + q) * NPCA + c);
        }
    }
    __syncthreads();

    // ---- stage 1a (all 256 threads): (bb, j) -> R, regressed joints ----
    const int bb = tid >> 4;
    const int j  = tid & 15;
    float R[9];
    float jx[3];
    {
        float p0, p1, p2;
        if (j == 0) {
            const int b = b0 + bb;
            p0 = ldv<T>(orient, (size_t)b * 3 + 0) + ldv<T>(pose_mean, 0);
            p1 = ldv<T>(orient, (size_t)b * 3 + 1) + ldv<T>(pose_mean, 1);
            p2 = ldv<T>(orient, (size_t)b * 3 + 2) + ldv<T>(pose_mean, 2);
        } else {
            int base = 3 * (j - 1);
            p0 = ldv<T>(pose_mean, 3 * j + 0);
            p1 = ldv<T>(pose_mean, 3 * j + 1);
            p2 = ldv<T>(pose_mean, 3 * j + 2);
            #pragma unroll
            for (int c = 0; c < NPCA; ++c) {
                float hpv = s.hp[bb][c];
                p0 += hpv * ldv<T>(hc, c * 45 + base + 0);
                p1 += hpv * ldv<T>(hc, c * 45 + base + 1);
                p2 += hpv * ldv<T>(hc, c * 45 + base + 2);
            }
        }

        float r0 = p0 + 1e-8f, r1 = p1 + 1e-8f, r2 = p2 + 1e-8f;
        float angle = sqrtf(r0 * r0 + r1 * r1 + r2 * r2);
        float inv = 1.f / angle;
        float ax = p0 * inv, ay = p1 * inv, az = p2 * inv;
        float sn = sinf(angle);
        float cc1 = 1.f - cosf(angle);
        R[0] = 1.f + cc1 * (-az * az - ay * ay);
        R[1] = -sn * az + cc1 * ax * ay;
        R[2] =  sn * ay + cc1 * ax * az;
        R[3] =  sn * az + cc1 * ax * ay;
        R[4] = 1.f + cc1 * (-az * az - ax * ax);
        R[5] = -sn * ax + cc1 * ay * az;
        R[6] = -sn * ay + cc1 * ax * az;
        R[7] =  sn * ax + cc1 * ay * az;
        R[8] = 1.f + cc1 * (-ax * ax - ay * ay);

        #pragma unroll
        for (int k = 0; k < 3; ++k) {
            float acc = jt[j * 3 + k];
            #pragma unroll
            for (int l = 0; l < NSHAPE; ++l)
                acc += jsd[(j * 3 + k) * NSHAPE + l] * s.beta[bb][l];
            jx[k] = acc;
            s.joints[bb][j][k] = acc;
        }
    }
    __syncthreads();

    // ---- stage 1b: local transform [R | joint - parent_joint] ----
    {
        int par = parent_of(j);
        #pragma unroll
        for (int m = 0; m < 3; ++m) {
            float t = jx[m] - (j > 0 ? s.joints[bb][par][m] : 0.f);
            s.tmrel[bb][j][m * 4 + 0] = R[m * 3 + 0];
            s.tmrel[bb][j][m * 4 + 1] = R[m * 3 + 1];
            s.tmrel[bb][j][m * 4 + 2] = R[m * 3 + 2];
            s.tmrel[bb][j][m * 4 + 3] = t;
        }
    }
    __syncthreads();

    // ---- stage 1c: chain walk (reads tmrel as tm) ----
    float G[12];
    {
        int stack[3];
        int depth = 0;
        int i = j;
        while (i != 0 && depth < 3) { stack[depth++] = i; i = parent_of(i); }

        #pragma unroll
        for (int t = 0; t < 12; ++t) G[t] = s.tmrel[bb][0][t];
        for (int d = depth - 1; d >= 0; --d) {
            const float* Tc = s.tmrel[bb][stack[d]];
            float Gn[12];
            #pragma unroll
            for (int m = 0; m < 3; ++m) {
                #pragma unroll
                for (int n = 0; n < 4; ++n) {
                    float acc = G[m * 4 + 0] * Tc[0 * 4 + n] +
                                G[m * 4 + 1] * Tc[1 * 4 + n] +
                                G[m * 4 + 2] * Tc[2 * 4 + n];
                    if (n == 3) acc += G[m * 4 + 3];
                    Gn[m * 4 + n] = acc;
                }
            }
            #pragma unroll
            for (int t = 0; t < 12; ++t) G[t] = Gn[t];
        }
    }
    __syncthreads();   // everyone done READING tm; now overwrite with rel

    {
        // posed joints out (+ transl)
        size_t jo = VERT_ELEMS + ((size_t)(b0 + bb) * NJOINT + j) * 3;
        st3<T>(out_base, jo,
               G[0 * 4 + 3] + s.transl[bb][0],
               G[1 * 4 + 3] + s.transl[bb][1],
               G[2 * 4 + 3] + s.transl[bb][2]);

        // rel transform: [R_full | t - R_full @ joint]
        #pragma unroll
        for (int m = 0; m < 3; ++m) {
            float rb = G[m * 4 + 3] -
                       (G[m * 4 + 0] * jx[0] + G[m * 4 + 1] * jx[1] + G[m * 4 + 2] * jx[2]);
            s.tmrel[bb][j][m * 4 + 0] = G[m * 4 + 0];
            s.tmrel[bb][j][m * 4 + 1] = G[m * 4 + 1];
            s.tmrel[bb][j][m * 4 + 2] = G[m * 4 + 2];
            s.tmrel[bb][j][m * 4 + 3] = rb;
        }

        if (j > 0) {
            float* po = s.pf[bb] + (j - 1) * 9;
            po[0] = R[0] - 1.f; po[1] = R[1];       po[2] = R[2];
            po[3] = R[3];       po[4] = R[4] - 1.f; po[5] = R[5];
            po[6] = R[6];       po[7] = R[7];       po[8] = R[8] - 1.f;
        } else {
            s.pf[bb][135] = 0.f;   // pad so float4 chunk 33 is harmless
        }
    }
    __syncthreads();

    // ---- stage 2: per-vertex, all BB batches in registers ----
    for (int v = tid; v < NVERT; v += 256) {
        const int v3 = v * 3;

        float a[BB][3];
        {
            const float t0 = ldv<T>(v_template, v3 + 0);
            const float t1 = ldv<T>(v_template, v3 + 1);
            const float t2 = ldv<T>(v_template, v3 + 2);
            #pragma unroll
            for (int q = 0; q < BB; ++q) { a[q][0] = t0; a[q][1] = t1; a[q][2] = t2; }
        }

        // shape blendshapes: 30 loads serve 16 batches
        #pragma unroll
        for (int l = 0; l < NSHAPE; ++l) {
            const float sd0 = ldv<T>(shapedirs, (size_t)v * 30 + 0 * NSHAPE + l);
            const float sd1 = ldv<T>(shapedirs, (size_t)v * 30 + 1 * NSHAPE + l);
            const float sd2 = ldv<T>(shapedirs, (size_t)v * 30 + 2 * NSHAPE + l);
            #pragma unroll
            for (int q = 0; q < BB; ++q) {
                const float be = s.beta[q][l];
                a[q][0] += be * sd0;
                a[q][1] += be * sd1;
                a[q][2] += be * sd2;
            }
        }

        // pose blendshapes
        if constexpr (TRP) {
            // manual 1-chunk-ahead double buffer; chunk 34 is zeros.
            const float4* __restrict__ pdT4 = (const float4*)pdT;
            float4 px = pdT4[(size_t)v3 + 0];
            float4 py = pdT4[(size_t)v3 + 1];
            float4 pz = pdT4[(size_t)v3 + 2];
            #pragma unroll 2
            for (int c = 0; c < NCHUNK; ++c) {
                const size_t nb = (size_t)(c + 1) * PD_COLS + v3;
                float4 nx = pdT4[nb + 0];
                float4 ny = pdT4[nb + 1];
                float4 nz = pdT4[nb + 2];
                #pragma unroll
                for (int q = 0; q < BB; ++q) {
                    const float4 f = *(const float4*)&s.pf[q][c * 4];
                    a[q][0] += f.x * px.x + f.y * px.y + f.z * px.z + f.w * px.w;
                    a[q][1] += f.x * py.x + f.y * py.y + f.z * py.z + f.w * py.w;
                    a[q][2] += f.x * pz.x + f.y * pz.y + f.z * pz.z + f.w * pz.w;
                }
                px = nx; py = ny; pz = nz;
            }
        } else {
            #pragma unroll 1
            for (int c = 0; c < NCHUNK; ++c) {
                const int p = c * 4;
                float pdx[4], pdy[4], pdz[4];
                #pragma unroll
                for (int qq = 0; qq < 3; ++qq) {
                    pdx[qq] = ldv<T>(posedirs, (size_t)(p + qq) * PD_COLS + v3 + 0);
                    pdy[qq] = ldv<T>(posedirs, (size_t)(p + qq) * PD_COLS + v3 + 1);
                    pdz[qq] = ldv<T>(posedirs, (size_t)(p + qq) * PD_COLS + v3 + 2);
                }
                if (p + 3 < NPF) {
                    pdx[3] = ldv<T>(posedirs, (size_t)(p + 3) * PD_COLS + v3 + 0);
                    pdy[3] = ldv<T>(posedirs, (size_t)(p + 3) * PD_COLS + v3 + 1);
                    pdz[3] = ldv<T>(posedirs, (size_t)(p + 3) * PD_COLS + v3 + 2);
                } else {
                    pdx[3] = 0.f; pdy[3] = 0.f; pdz[3] = 0.f;
                }
                #pragma unroll
                for (int q = 0; q < BB; ++q) {
                    const float4 f = *(const float4*)&s.pf[q][p];
                    a[q][0] += f.x * pdx[0] + f.y * pdx[1] + f.z * pdx[2] + f.w * pdx[3];
                    a[q][1] += f.x * pdy[0] + f.y * pdy[1] + f.z * pdy[2] + f.w * pdy[3];
                    a[q][2] += f.x * pdz[0] + f.y * pdz[1] + f.z * pdz[2] + f.w * pdz[3];
                }
            }
        }

        // LBS weights
        float w[NJOINT];
        if constexpr (sizeof(T) == 4) {
            const float4* wl = (const float4*)((const float*)lbsw + (size_t)v * NJOINT);
            #pragma unroll
            for (int g = 0; g < 4; ++g) {
                const float4 t = wl[g];
                w[g * 4 + 0] = t.x; w[g * 4 + 1] = t.y;
                w[g * 4 + 2] = t.z; w[g * 4 + 3] = t.w;
            }
        } else {
            #pragma unroll
            for (int jj = 0; jj < NJOINT; ++jj)
                w[jj] = ldv<T>(lbsw, (size_t)v * NJOINT + jj);
        }

        // LBS + output. rel rows read as uniform float4 broadcasts.
        #pragma unroll
        for (int q = 0; q < BB; ++q) {
            float Tm[12];
            #pragma unroll
            for (int t = 0; t < 12; ++t) Tm[t] = 0.f;
            #pragma unroll
            for (int jj = 0; jj < NJOINT; ++jj) {
                const float4 r0 = *(const float4*)&s.tmrel[q][jj][0];
                const float4 r1 = *(const float4*)&s.tmrel[q][jj][4];
                const float4 r2 = *(const float4*)&s.tmrel[q][jj][8];
                const float wj = w[jj];
                Tm[0] += wj * r0.x; Tm[1]  += wj * r0.y; Tm[2]  += wj * r0.z; Tm[3]  += wj * r0.w;
                Tm[4] += wj * r1.x; Tm[5]  += wj * r1.y; Tm[6]  += wj * r1.z; Tm[7]  += wj * r1.w;
                Tm[8] += wj * r2.x; Tm[9]  += wj * r2.y; Tm[10] += wj * r2.z; Tm[11] += wj * r2.w;
            }
            const size_t vo = ((size_t)(b0 + q) * NVERT + v) * 3;
            const float o0 = Tm[0] * a[q][0] + Tm[1] * a[q][1] + Tm[2]  * a[q][2] + Tm[3]  + s.transl[q][0];
            const float o1 = Tm[4] * a[q][0] + Tm[5] * a[q][1] + Tm[6]  * a[q][2] + Tm[7]  + s.transl[q][1];
            const float o2 = Tm[8] * a[q][0] + Tm[9] * a[q][1] + Tm[10] * a[q][2] + Tm[11] + s.transl[q][2];
            st3<T>(out_base, vo, o0, o1, o2);
        }
    }
}

template <bool TRP>
__global__ __launch_bounds__(256, 4) void mano_fused(
    const void* betas, const void* orient, const void* hand_pose,
    const void* transl, const void* hc, const void* pose_mean,
    const void* v_template, const void* shapedirs, const void* posedirs,
    const void* lbsw, const int* __restrict__ flag,
    const float* __restrict__ jt, const float* __restrict__ jsd,
    const float* __restrict__ pdT,
    void* out_base) {
    __shared__ SmemB s;
    if (*flag)
        mano_body<float, TRP>(betas, orient, hand_pose, transl, hc, pose_mean,
                              v_template, shapedirs, posedirs, lbsw, jt, jsd, pdT,
                              out_base, s);
    else
        mano_body<bf16, TRP>(betas, orient, hand_pose, transl, hc, pose_mean,
                             v_template, shapedirs, posedirs, lbsw, jt, jsd, pdT,
                             out_base, s);
}

// ---------------------------------------------------------------------------
extern "C" void kernel_launch(void* const* d_in, const int* in_sizes, int n_in,
                              void* d_out, int out_size, void* d_ws, size_t ws_size,
                              hipStream_t stream) {
    const void* betas      = d_in[0];
    const void* orient     = d_in[1];
    const void* hand_pose  = d_in[2];
    const void* transl     = d_in[3];
    const void* hc         = d_in[4];
    const void* pose_mean  = d_in[5];
    const void* v_template = d_in[6];
    const void* shapedirs  = d_in[7];
    const void* posedirs   = d_in[8];
    const void* Jreg       = d_in[9];
    const void* lbsw       = d_in[10];
    // d_in[11] (parents) intentionally ignored — tree is hardcoded.

    int*   flag = (int*)d_ws;
    float* jt   = (float*)d_ws + 16;
    float* jsd  = (float*)d_ws + 64;
    float* pdT  = (float*)((char*)d_ws + PDT_BYTE_OFF);

    const bool trp = ws_size >= (size_t)PDT_BYTE_OFF + (size_t)PDT_ELEMS * 4;

    hipLaunchKernelGGL(detect_dtype, dim3(1), dim3(256), 0, stream,
                       (const u16*)betas, flag);
    hipLaunchKernelGGL(precompute_kernel, dim3(3), dim3(192), 0, stream,
                       Jreg, v_template, shapedirs, flag, jt, jsd);
    if (trp) {
        hipLaunchKernelGGL(transpose_kernel, dim3((PDT_ELEMS + 255) / 256), dim3(256),
                           0, stream, posedirs, flag, pdT);
        hipLaunchKernelGGL(mano_fused<true>, dim3(NBLK), dim3(256), 0, stream,
                           betas, orient, hand_pose, transl, hc, pose_mean,
                           v_template, shapedirs, posedirs, lbsw, flag, jt, jsd,
                           pdT, d_out);
    } else {
        hipLaunchKernelGGL(mano_fused<false>, dim3(NBLK), dim3(256), 0, stream,
                           betas, orient, hand_pose, transl, hc, pose_mean,
                           v_template, shapedirs, posedirs, lbsw, flag, jt, jsd,
                           pdT, d_out);
    }
    (void)in_sizes; (void)n_in; (void)out_size; (void)ws_size;
}

// Round 5
// 1357.628 us; speedup vs baseline: 1.9382x; 1.5370x over previous
//
#include <hip/hip_runtime.h>
#include <hip/hip_bf16.h>

// MANO forward: B=16384, V=778, J=16, NB=10, NPCA=6.
// R6: (1) wave-local LDS-staged output with 64-lane contiguous NT u32
// copies (R5b showed per-scalar NT stores write through at 32-B sector
// granularity: 38M lane-stores * 32B ~= the measured 1.4GB WRITE);
// (2) pdT stored in input dtype (bf16 mode: lossless, halves pdT traffic);
// (3) depth-2 register prefetch on pdT chunks (2-chunk unrolled pipeline)
// to raise memory-level parallelism (R5b was HBM-latency-bound at 1.1TB/s
// fetch with 1-deep prefetch). LDS 37.6KB -> 4 blocks/CU.

typedef __hip_bfloat16 bf16;
typedef unsigned short u16;
typedef unsigned int u32;

#define BATCH 16384
#define NVERT 778
#define NJOINT 16
#define NSHAPE 10
#define NPCA 6
#define NPF 135                // (J-1)*9
#define PD_COLS (NVERT * 3)    // 2334
#define VERT_ELEMS ((size_t)BATCH * NVERT * 3)
#define BB 16                  // batches per block
#define NBLK (BATCH / BB)      // 1024
#define NCHUNK 34              // ceil(135/4)
#define PDT_CHUNKS 36          // +2 zero-padded chunks for depth-2 prefetch
#define PDT_ELEMS (PDT_CHUNKS * PD_COLS * 4)   // 336,096 elements
#define PDT_BYTE_OFF 4096

__device__ __forceinline__ float b2f(bf16 x) { return __bfloat162float(x); }
__device__ __forceinline__ bf16  f2b(float x) { return __float2bfloat16(x); }

// PARENTS = [-1,0,1,2,0,4,5,0,7,8,0,10,11,0,13,14]
__device__ __forceinline__ int parent_of(int j) {
    return (j == 0) ? -1 : (((j - 1) % 3 == 0) ? 0 : j - 1);
}

template <typename T> __device__ __forceinline__ float ldv(const void* p, size_t i);
template <> __device__ __forceinline__ float ldv<float>(const void* p, size_t i) {
    return ((const float*)p)[i];
}
template <> __device__ __forceinline__ float ldv<bf16>(const void* p, size_t i) {
    return b2f(((const bf16*)p)[i]);
}

template <typename T> __device__ __forceinline__ void stv(void* p, size_t i, float v);
template <> __device__ __forceinline__ void stv<float>(void* p, size_t i, float v) {
    ((float*)p)[i] = v;
}
template <> __device__ __forceinline__ void stv<bf16>(void* p, size_t i, float v) {
    ((bf16*)p)[i] = f2b(v);
}

__device__ __forceinline__ u16 bf_bits(float x) {
    union { bf16 h; u16 u; } cvt;
    cvt.h = f2b(x);
    return cvt.u;
}
__device__ __forceinline__ float bflo(u32 u) {
    union { u32 i; float f; } t; t.i = u << 16; return t.f;
}
__device__ __forceinline__ float bfhi(u32 u) {
    union { u32 i; float f; } t; t.i = u & 0xffff0000u; return t.f;
}
__device__ __forceinline__ float4 bf4(uint2 u) {
    float4 f;
    f.x = bflo(u.x); f.y = bfhi(u.x);
    f.z = bflo(u.y); f.w = bfhi(u.y);
    return f;
}

// ---------------------------------------------------------------------------
// Kernel 0: dtype detector. flag=1 -> fp32.
// ---------------------------------------------------------------------------
__global__ void detect_dtype(const u16* __restrict__ betas_u, int* __restrict__ flag) {
    __shared__ int s_cnt[256];
    int tid = threadIdx.x;
    int cnt = 0;
    for (int i = tid; i < BATCH * NSHAPE; i += 256) {
        int e = (betas_u[i] >> 7) & 0xFF;
        cnt += (e >= 134) ? 1 : 0;
    }
    s_cnt[tid] = cnt;
    __syncthreads();
    for (int s = 128; s > 0; s >>= 1) {
        if (tid < s) s_cnt[tid] += s_cnt[tid + s];
        __syncthreads();
    }
    if (tid == 0) *flag = (s_cnt[0] > 1000) ? 1 : 0;
}

// ---------------------------------------------------------------------------
// Kernel A: fold J_regressor into v_template and shapedirs.
// ---------------------------------------------------------------------------
template <typename T>
__device__ void precompute_body(const void* Jreg, const void* v_template,
                                const void* shapedirs, float* jt, float* jsd) {
    int idx = blockIdx.x * blockDim.x + threadIdx.x;
    if (idx >= 48 + 480) return;
    if (idx < 48) {
        int j = idx / 3, k = idx % 3;
        float acc = 0.f;
        for (int v = 0; v < NVERT; ++v)
            acc += ldv<T>(Jreg, j * NVERT + v) * ldv<T>(v_template, v * 3 + k);
        jt[idx] = acc;
    } else {
        int o = idx - 48;
        int jk = o / NSHAPE, l = o % NSHAPE;
        int j = jk / 3, k = jk % 3;
        float acc = 0.f;
        for (int v = 0; v < NVERT; ++v)
            acc += ldv<T>(Jreg, j * NVERT + v) * ldv<T>(shapedirs, (v * 3 + k) * NSHAPE + l);
        jsd[o] = acc;
    }
}

__global__ void precompute_kernel(const void* Jreg, const void* v_template,
                                  const void* shapedirs, const int* __restrict__ flag,
                                  float* jt, float* jsd) {
    if (*flag) precompute_body<float>(Jreg, v_template, shapedirs, jt, jsd);
    else       precompute_body<bf16 >(Jreg, v_template, shapedirs, jt, jsd);
}

// ---------------------------------------------------------------------------
// Kernel A2: transpose posedirs -> pdT[c][r][j] = posedirs[4c+j][r], stored
// in the INPUT dtype (bf16 mode: lossless raw copy -> half the read bytes).
// Zero-padded for p >= 135 (incl. chunks 34,35 for branchless prefetch).
// ---------------------------------------------------------------------------
template <typename T>
__device__ void transpose_body(const void* pd, void* pdT) {
    int idx = blockIdx.x * blockDim.x + threadIdx.x;
    if (idx >= PDT_ELEMS) return;
    int j = idx & 3;
    int rc = idx >> 2;
    int r = rc % PD_COLS;
    int c = rc / PD_COLS;
    int p = c * 4 + j;
    float val = (p < NPF) ? ldv<T>(pd, (size_t)p * PD_COLS + r) : 0.f;
    stv<T>(pdT, idx, val);
}

__global__ void transpose_kernel(const void* pd, const int* __restrict__ flag,
                                 void* pdT) {
    if (*flag) transpose_body<float>(pd, pdT);
    else       transpose_body<bf16 >(pd, pdT);
}

// ---------------------------------------------------------------------------
// Kernel B: fused batch-tiled kernel. blockIdx.x = batch-tile of BB. 256 thr.
// ---------------------------------------------------------------------------
struct __align__(16) SmemB {
    float pf[BB][136];            // 135 + zero pad for float4 chunks   8704 B
    float tmrel[BB][NJOINT][12];  // stage1: local tm; then rel        12288 B
    float joints[BB][NJOINT][3];  //                                    3072 B
    float beta[BB][NSHAPE];       //                                     640 B
    float transl[BB][3];          //                                     192 B
    float hp[BB][NPCA];           //                                     384 B
    float ob[4][4][192];          // per-wave output staging           12288 B
};                                // 37,568 B -> 4 blocks/CU by LDS

template <typename T, bool TRP>
__device__ void mano_body(const void* betas, const void* orient,
                          const void* hand_pose, const void* transl,
                          const void* hc, const void* pose_mean,
                          const void* v_template, const void* shapedirs,
                          const void* posedirs, const void* lbsw,
                          const float* __restrict__ jt, const float* __restrict__ jsd,
                          const void* __restrict__ pdTv,
                          void* out_base, SmemB& s) {
    const int tid = threadIdx.x;
    const int b0 = blockIdx.x * BB;

    // ---- stage 0: stage per-batch small inputs into LDS ----
    if (tid < BB * NSHAPE) {                       // 160 threads
        int q = tid / NSHAPE, l = tid % NSHAPE;
        s.beta[q][l] = ldv<T>(betas, (size_t)(b0 + q) * NSHAPE + l);
    } else if (tid < BB * NSHAPE + BB * 3) {       // 48 threads
        int o = tid - BB * NSHAPE;
        int q = o / 3, k = o % 3;
        s.transl[q][k] = ldv<T>(transl, (size_t)(b0 + q) * 3 + k);
    } else {                                       // 48 threads, 2 loads each
        int o = tid - (BB * NSHAPE + BB * 3);
        #pragma unroll
        for (int rep = 0; rep < 2; ++rep) {
            int oo = o + rep * 48;
            int q = oo / NPCA, c = oo % NPCA;
            s.hp[q][c] = ldv<T>(hand_pose, (size_t)(b0 + q) * NPCA + c);
        }
    }
    __syncthreads();

    // ---- stage 1a (all 256 threads): (bb, j) -> R, regressed joints ----
    const int bb = tid >> 4;
    const int j  = tid & 15;
    float R[9];
    float jx[3];
    {
        float p0, p1, p2;
        if (j == 0) {
            const int b = b0 + bb;
            p0 = ldv<T>(orient, (size_t)b * 3 + 0) + ldv<T>(pose_mean, 0);
            p1 = ldv<T>(orient, (size_t)b * 3 + 1) + ldv<T>(pose_mean, 1);
            p2 = ldv<T>(orient, (size_t)b * 3 + 2) + ldv<T>(pose_mean, 2);
        } else {
            int base = 3 * (j - 1);
            p0 = ldv<T>(pose_mean, 3 * j + 0);
            p1 = ldv<T>(pose_mean, 3 * j + 1);
            p2 = ldv<T>(pose_mean, 3 * j + 2);
            #pragma unroll
            for (int c = 0; c < NPCA; ++c) {
                float hpv = s.hp[bb][c];
                p0 += hpv * ldv<T>(hc, c * 45 + base + 0);
                p1 += hpv * ldv<T>(hc, c * 45 + base + 1);
                p2 += hpv * ldv<T>(hc, c * 45 + base + 2);
            }
        }

        float r0 = p0 + 1e-8f, r1 = p1 + 1e-8f, r2 = p2 + 1e-8f;
        float angle = sqrtf(r0 * r0 + r1 * r1 + r2 * r2);
        float inv = 1.f / angle;
        float ax = p0 * inv, ay = p1 * inv, az = p2 * inv;
        float sn = sinf(angle);
        float cc1 = 1.f - cosf(angle);
        R[0] = 1.f + cc1 * (-az * az - ay * ay);
        R[1] = -sn * az + cc1 * ax * ay;
        R[2] =  sn * ay + cc1 * ax * az;
        R[3] =  sn * az + cc1 * ax * ay;
        R[4] = 1.f + cc1 * (-az * az - ax * ax);
        R[5] = -sn * ax + cc1 * ay * az;
        R[6] = -sn * ay + cc1 * ax * az;
        R[7] =  sn * ax + cc1 * ay * az;
        R[8] = 1.f + cc1 * (-ax * ax - ay * ay);

        #pragma unroll
        for (int k = 0; k < 3; ++k) {
            float acc = jt[j * 3 + k];
            #pragma unroll
            for (int l = 0; l < NSHAPE; ++l)
                acc += jsd[(j * 3 + k) * NSHAPE + l] * s.beta[bb][l];
            jx[k] = acc;
            s.joints[bb][j][k] = acc;
        }
    }
    __syncthreads();

    // ---- stage 1b: local transform [R | joint - parent_joint] ----
    {
        int par = parent_of(j);
        #pragma unroll
        for (int m = 0; m < 3; ++m) {
            float t = jx[m] - (j > 0 ? s.joints[bb][par][m] : 0.f);
            s.tmrel[bb][j][m * 4 + 0] = R[m * 3 + 0];
            s.tmrel[bb][j][m * 4 + 1] = R[m * 3 + 1];
            s.tmrel[bb][j][m * 4 + 2] = R[m * 3 + 2];
            s.tmrel[bb][j][m * 4 + 3] = t;
        }
    }
    __syncthreads();

    // ---- stage 1c: chain walk (reads tmrel as tm) ----
    float G[12];
    {
        int stack[3];
        int depth = 0;
        int i = j;
        while (i != 0 && depth < 3) { stack[depth++] = i; i = parent_of(i); }

        #pragma unroll
        for (int t = 0; t < 12; ++t) G[t] = s.tmrel[bb][0][t];
        for (int d = depth - 1; d >= 0; --d) {
            const float* Tc = s.tmrel[bb][stack[d]];
            float Gn[12];
            #pragma unroll
            for (int m = 0; m < 3; ++m) {
                #pragma unroll
                for (int n = 0; n < 4; ++n) {
                    float acc = G[m * 4 + 0] * Tc[0 * 4 + n] +
                                G[m * 4 + 1] * Tc[1 * 4 + n] +
                                G[m * 4 + 2] * Tc[2 * 4 + n];
                    if (n == 3) acc += G[m * 4 + 3];
                    Gn[m * 4 + n] = acc;
                }
            }
            #pragma unroll
            for (int t = 0; t < 12; ++t) G[t] = Gn[t];
        }
    }
    __syncthreads();   // everyone done READING tm; now overwrite with rel

    {
        // posed joints out (+ transl) — small, plain cached stores
        size_t jo = VERT_ELEMS + ((size_t)(b0 + bb) * NJOINT + j) * 3;
        stv<T>(out_base, jo + 0, G[0 * 4 + 3] + s.transl[bb][0]);
        stv<T>(out_base, jo + 1, G[1 * 4 + 3] + s.transl[bb][1]);
        stv<T>(out_base, jo + 2, G[2 * 4 + 3] + s.transl[bb][2]);

        // rel transform: [R_full | t - R_full @ joint]
        #pragma unroll
        for (int m = 0; m < 3; ++m) {
            float rb = G[m * 4 + 3] -
                       (G[m * 4 + 0] * jx[0] + G[m * 4 + 1] * jx[1] + G[m * 4 + 2] * jx[2]);
            s.tmrel[bb][j][m * 4 + 0] = G[m * 4 + 0];
            s.tmrel[bb][j][m * 4 + 1] = G[m * 4 + 1];
            s.tmrel[bb][j][m * 4 + 2] = G[m * 4 + 2];
            s.tmrel[bb][j][m * 4 + 3] = rb;
        }

        if (j > 0) {
            float* po = s.pf[bb] + (j - 1) * 9;
            po[0] = R[0] - 1.f; po[1] = R[1];       po[2] = R[2];
            po[3] = R[3];       po[4] = R[4] - 1.f; po[5] = R[5];
            po[6] = R[6];       po[7] = R[7];       po[8] = R[8] - 1.f;
        } else {
            s.pf[bb][135] = 0.f;   // pad so float4 chunk 33 is harmless
        }
    }
    __syncthreads();

    // ---- stage 2: per-vertex, all BB batches in registers ----
    // NO __syncthreads below (wave-local staging only) -> ragged exit safe.
    const int wv = tid >> 6;
    const int ln = tid & 63;

    for (int iter = 0; iter < 4; ++iter) {
        const int vbase = iter * 256 + wv * 64;
        if (vbase >= NVERT) break;                 // uniform per wave
        const int nv = (NVERT - vbase < 64) ? (NVERT - vbase) : 64;
        const int v  = vbase + ln;
        const int vc = (v < NVERT) ? v : (NVERT - 1);   // clamp for loads
        const int v3 = vc * 3;

        float a[BB][3];
        {
            const float t0 = ldv<T>(v_template, v3 + 0);
            const float t1 = ldv<T>(v_template, v3 + 1);
            const float t2 = ldv<T>(v_template, v3 + 2);
            #pragma unroll
            for (int q = 0; q < BB; ++q) { a[q][0] = t0; a[q][1] = t1; a[q][2] = t2; }
        }

        // shape blendshapes: 30 loads serve 16 batches
        #pragma unroll
        for (int l = 0; l < NSHAPE; ++l) {
            const float sd0 = ldv<T>(shapedirs, (size_t)vc * 30 + 0 * NSHAPE + l);
            const float sd1 = ldv<T>(shapedirs, (size_t)vc * 30 + 1 * NSHAPE + l);
            const float sd2 = ldv<T>(shapedirs, (size_t)vc * 30 + 2 * NSHAPE + l);
            #pragma unroll
            for (int q = 0; q < BB; ++q) {
                const float be = s.beta[q][l];
                a[q][0] += be * sd0;
                a[q][1] += be * sd1;
                a[q][2] += be * sd2;
            }
        }

        // pose blendshapes: depth-2 prefetch, 2-chunk unrolled pipeline
        auto fma_chunk = [&](float4 px, float4 py, float4 pz, int c) {
            #pragma unroll
            for (int q = 0; q < BB; ++q) {
                const float4 f = *(const float4*)&s.pf[q][c * 4];
                a[q][0] += f.x * px.x + f.y * px.y + f.z * px.z + f.w * px.w;
                a[q][1] += f.x * py.x + f.y * py.y + f.z * py.z + f.w * py.w;
                a[q][2] += f.x * pz.x + f.y * pz.y + f.z * pz.z + f.w * pz.w;
            }
        };

        if constexpr (TRP) {
            if constexpr (sizeof(T) == 4) {
                const float4* __restrict__ pdT4 = (const float4*)pdTv;
                float4 ax = pdT4[(size_t)0 * PD_COLS + v3 + 0];
                float4 ay = pdT4[(size_t)0 * PD_COLS + v3 + 1];
                float4 az = pdT4[(size_t)0 * PD_COLS + v3 + 2];
                float4 bx = pdT4[(size_t)1 * PD_COLS + v3 + 0];
                float4 by = pdT4[(size_t)1 * PD_COLS + v3 + 1];
                float4 bz = pdT4[(size_t)1 * PD_COLS + v3 + 2];
                #pragma unroll 1
                for (int c = 0; c < NCHUNK; c += 2) {
                    const size_t n2 = (size_t)(c + 2) * PD_COLS + v3;
                    float4 cx = pdT4[n2 + 0], cy = pdT4[n2 + 1], cz = pdT4[n2 + 2];
                    fma_chunk(ax, ay, az, c);
                    const size_t n3 = (size_t)(c + 3) * PD_COLS + v3;
                    float4 dx = pdT4[n3 + 0], dy = pdT4[n3 + 1], dz = pdT4[n3 + 2];
                    fma_chunk(bx, by, bz, c + 1);
                    ax = cx; ay = cy; az = cz;
                    bx = dx; by = dy; bz = dz;
                }
            } else {
                const uint2* __restrict__ pdT2 = (const uint2*)pdTv;
                uint2 ax = pdT2[(size_t)0 * PD_COLS + v3 + 0];
                uint2 ay = pdT2[(size_t)0 * PD_COLS + v3 + 1];
                uint2 az = pdT2[(size_t)0 * PD_COLS + v3 + 2];
                uint2 bx = pdT2[(size_t)1 * PD_COLS + v3 + 0];
                uint2 by = pdT2[(size_t)1 * PD_COLS + v3 + 1];
                uint2 bz = pdT2[(size_t)1 * PD_COLS + v3 + 2];
                #pragma unroll 1
                for (int c = 0; c < NCHUNK; c += 2) {
                    const size_t n2 = (size_t)(c + 2) * PD_COLS + v3;
                    uint2 cx = pdT2[n2 + 0], cy = pdT2[n2 + 1], cz = pdT2[n2 + 2];
                    fma_chunk(bf4(ax), bf4(ay), bf4(az), c);
                    const size_t n3 = (size_t)(c + 3) * PD_COLS + v3;
                    uint2 dx = pdT2[n3 + 0], dy = pdT2[n3 + 1], dz = pdT2[n3 + 2];
                    fma_chunk(bf4(bx), bf4(by), bf4(bz), c + 1);
                    ax = cx; ay = cy; az = cz;
                    bx = dx; by = dy; bz = dz;
                }
            }
        } else {
            #pragma unroll 1
            for (int c = 0; c < NCHUNK; ++c) {
                const int p = c * 4;
                float pdx[4], pdy[4], pdz[4];
                #pragma unroll
                for (int qq = 0; qq < 3; ++qq) {
                    pdx[qq] = ldv<T>(posedirs, (size_t)(p + qq) * PD_COLS + v3 + 0);
                    pdy[qq] = ldv<T>(posedirs, (size_t)(p + qq) * PD_COLS + v3 + 1);
                    pdz[qq] = ldv<T>(posedirs, (size_t)(p + qq) * PD_COLS + v3 + 2);
                }
                if (p + 3 < NPF) {
                    pdx[3] = ldv<T>(posedirs, (size_t)(p + 3) * PD_COLS + v3 + 0);
                    pdy[3] = ldv<T>(posedirs, (size_t)(p + 3) * PD_COLS + v3 + 1);
                    pdz[3] = ldv<T>(posedirs, (size_t)(p + 3) * PD_COLS + v3 + 2);
                } else {
                    pdx[3] = 0.f; pdy[3] = 0.f; pdz[3] = 0.f;
                }
                float4 px = make_float4(pdx[0], pdx[1], pdx[2], pdx[3]);
                float4 py = make_float4(pdy[0], pdy[1], pdy[2], pdy[3]);
                float4 pz = make_float4(pdz[0], pdz[1], pdz[2], pdz[3]);
                fma_chunk(px, py, pz, c);
            }
        }

        // LBS weights (wide loads both dtypes)
        float w[NJOINT];
        if constexpr (sizeof(T) == 4) {
            const float4* wl = (const float4*)((const float*)lbsw + (size_t)vc * NJOINT);
            #pragma unroll
            for (int g = 0; g < 4; ++g) {
                const float4 t = wl[g];
                w[g * 4 + 0] = t.x; w[g * 4 + 1] = t.y;
                w[g * 4 + 2] = t.z; w[g * 4 + 3] = t.w;
            }
        } else {
            const uint4* wl = (const uint4*)((const u16*)lbsw + (size_t)vc * NJOINT);
            const uint4 w0 = wl[0], w1 = wl[1];
            w[0]  = bflo(w0.x); w[1]  = bfhi(w0.x);
            w[2]  = bflo(w0.y); w[3]  = bfhi(w0.y);
            w[4]  = bflo(w0.z); w[5]  = bfhi(w0.z);
            w[6]  = bflo(w0.w); w[7]  = bfhi(w0.w);
            w[8]  = bflo(w1.x); w[9]  = bfhi(w1.x);
            w[10] = bflo(w1.y); w[11] = bfhi(w1.y);
            w[12] = bflo(w1.z); w[13] = bfhi(w1.z);
            w[14] = bflo(w1.w); w[15] = bfhi(w1.w);
        }

        // LBS + wave-local staged output (4 q at a time through s.ob[wv])
        const int n32 = (nv * 3 * (int)sizeof(T)) >> 2;   // u32 words per q
        #pragma unroll 1
        for (int g = 0; g < 4; ++g) {
            #pragma unroll
            for (int qq = 0; qq < 4; ++qq) {
                const int q = g * 4 + qq;
                float Tm[12];
                #pragma unroll
                for (int t = 0; t < 12; ++t) Tm[t] = 0.f;
                #pragma unroll
                for (int jj = 0; jj < NJOINT; ++jj) {
                    const float4 r0 = *(const float4*)&s.tmrel[q][jj][0];
                    const float4 r1 = *(const float4*)&s.tmrel[q][jj][4];
                    const float4 r2 = *(const float4*)&s.tmrel[q][jj][8];
                    const float wj = w[jj];
                    Tm[0] += wj * r0.x; Tm[1]  += wj * r0.y; Tm[2]  += wj * r0.z; Tm[3]  += wj * r0.w;
                    Tm[4] += wj * r1.x; Tm[5]  += wj * r1.y; Tm[6]  += wj * r1.z; Tm[7]  += wj * r1.w;
                    Tm[8] += wj * r2.x; Tm[9]  += wj * r2.y; Tm[10] += wj * r2.z; Tm[11] += wj * r2.w;
                }
                const float o0 = Tm[0] * a[q][0] + Tm[1] * a[q][1] + Tm[2]  * a[q][2] + Tm[3]  + s.transl[q][0];
                const float o1 = Tm[4] * a[q][0] + Tm[5] * a[q][1] + Tm[6]  * a[q][2] + Tm[7]  + s.transl[q][1];
                const float o2 = Tm[8] * a[q][0] + Tm[9] * a[q][1] + Tm[10] * a[q][2] + Tm[11] + s.transl[q][2];
                if constexpr (sizeof(T) == 4) {
                    float* ob = &s.ob[wv][qq][0];
                    ob[ln * 3 + 0] = o0;
                    ob[ln * 3 + 1] = o1;
                    ob[ln * 3 + 2] = o2;
                } else {
                    u16* ob = (u16*)&s.ob[wv][qq][0];
                    ob[ln * 3 + 0] = bf_bits(o0);
                    ob[ln * 3 + 1] = bf_bits(o1);
                    ob[ln * 3 + 2] = bf_bits(o2);
                }
            }
            // copy out: 64-lane contiguous u32 NT stores (full 32B sectors)
            #pragma unroll
            for (int qq = 0; qq < 4; ++qq) {
                const int q = g * 4 + qq;
                const u32* src = (const u32*)&s.ob[wv][qq][0];
                u32* dst = (u32*)((char*)out_base +
                                  ((size_t)(b0 + q) * NVERT + vbase) * 3 * sizeof(T));
                #pragma unroll
                for (int k = 0; k < 3; ++k) {
                    const int idx = k * 64 + ln;
                    if (idx < n32) __builtin_nontemporal_store(src[idx], dst + idx);
                }
            }
        }
    }
}

template <bool TRP>
__global__ __launch_bounds__(256, 4) void mano_fused(
    const void* betas, const void* orient, const void* hand_pose,
    const void* transl, const void* hc, const void* pose_mean,
    const void* v_template, const void* shapedirs, const void* posedirs,
    const void* lbsw, const int* __restrict__ flag,
    const float* __restrict__ jt, const float* __restrict__ jsd,
    const void* __restrict__ pdT,
    void* out_base) {
    __shared__ SmemB s;
    if (*flag)
        mano_body<float, TRP>(betas, orient, hand_pose, transl, hc, pose_mean,
                              v_template, shapedirs, posedirs, lbsw, jt, jsd, pdT,
                              out_base, s);
    else
        mano_body<bf16, TRP>(betas, orient, hand_pose, transl, hc, pose_mean,
                             v_template, shapedirs, posedirs, lbsw, jt, jsd, pdT,
                             out_base, s);
}

// ---------------------------------------------------------------------------
extern "C" void kernel_launch(void* const* d_in, const int* in_sizes, int n_in,
                              void* d_out, int out_size, void* d_ws, size_t ws_size,
                              hipStream_t stream) {
    const void* betas      = d_in[0];
    const void* orient     = d_in[1];
    const void* hand_pose  = d_in[2];
    const void* transl     = d_in[3];
    const void* hc         = d_in[4];
    const void* pose_mean  = d_in[5];
    const void* v_template = d_in[6];
    const void* shapedirs  = d_in[7];
    const void* posedirs   = d_in[8];
    const void* Jreg       = d_in[9];
    const void* lbsw       = d_in[10];
    // d_in[11] (parents) intentionally ignored — tree is hardcoded.

    int*   flag = (int*)d_ws;
    float* jt   = (float*)d_ws + 16;
    float* jsd  = (float*)d_ws + 64;
    void*  pdT  = (void*)((char*)d_ws + PDT_BYTE_OFF);

    // worst case (fp32): 36 chunks * 2334 * 4 elems * 4 B
    const bool trp = ws_size >= (size_t)PDT_BYTE_OFF + (size_t)PDT_ELEMS * 4;

    hipLaunchKernelGGL(detect_dtype, dim3(1), dim3(256), 0, stream,
                       (const u16*)betas, flag);
    hipLaunchKernelGGL(precompute_kernel, dim3(3), dim3(192), 0, stream,
                       Jreg, v_template, shapedirs, flag, jt, jsd);
    if (trp) {
        hipLaunchKernelGGL(transpose_kernel, dim3((PDT_ELEMS + 255) / 256), dim3(256),
                           0, stream, posedirs, flag, pdT);
        hipLaunchKernelGGL(mano_fused<true>, dim3(NBLK), dim3(256), 0, stream,
                           betas, orient, hand_pose, transl, hc, pose_mean,
                           v_template, shapedirs, posedirs, lbsw, flag, jt, jsd,
                           pdT, d_out);
    } else {
        hipLaunchKernelGGL(mano_fused<false>, dim3(NBLK), dim3(256), 0, stream,
                           betas, orient, hand_pose, transl, hc, pose_mean,
                           v_template, shapedirs, posedirs, lbsw, flag, jt, jsd,
                           pdT, d_out);
    }
    (void)in_sizes; (void)n_in; (void)out_size; (void)ws_size;
}